// Round 1
// 154.856 us; speedup vs baseline: 1.0158x; 1.0158x over previous
//
#include <hip/hip_runtime.h>

#define N_NODES 50000
#define N_EDGES 800000
#define DIM 64
#define NEG_SLOPE 0.2f
#define NEG_INF (-__builtin_inff())
#define NB      3125         // 3125 blocks: 16 GEMM rows + 256 edges each (exact)
#define MAXDEG  128          // bucket capacity; Poisson(16) => P(>=128) ~ e^-90

typedef _Float16 half8 __attribute__((ext_vector_type(8)));

// K1 (uniform fusion): EVERY block does 16 rows of xm = x@W + bias AND 256
// edges of histogram+scatter (1 edge/thread). The atomicAdd is issued before
// the LDS staging loads, so its ~800-cycle device-scope round trip overlaps
// the staging latency and is fully absorbed by the __syncthreads drain; the
// scattered elist store is fired right after the barrier and drains under the
// 256-FMA GEMM loop. This replaces the 1-in-5 interleave, where all scatter
// work sat in 20% of blocks and ran latency-exposed after the cheap GEMM
// blocks drained (rocprof: VALUBusy 9%, hbm 15% — neither pipe busy).
__global__ __launch_bounds__(256) void k_pre(const float* __restrict__ x,
                                             const float* __restrict__ W,
                                             const float* __restrict__ b_msg,
                                             const float* __restrict__ b_edge,
                                             _Float16* __restrict__ xmh,
                                             const int* __restrict__ eidx,
                                             const float* __restrict__ eattr,
                                             unsigned* __restrict__ cnt,
                                             int2* __restrict__ elist) {
    __shared__ float Ws[DIM * DIM];   // 16 KB, row-major (scalar reads: 0-conflict)
    __shared__ float xs[16 * DIM];    // 4 KB
    int tid = threadIdx.x;
    int bid = blockIdx.x;

    // ---- edge part: issue loads + atomic FIRST (latency hidden below) ----
    int e = bid * 256 + tid;                    // 3125*256 == N_EDGES exactly
    int    esrc = eidx[e];
    int    edst = eidx[N_EDGES + e];
    float  ea   = eattr[e];
    unsigned r  = atomicAdd(cnt + edst, 1u);    // rank == final slot

    // ---- stage W (16 KB) and 16 rows of x into LDS ----
    const float4* W4 = (const float4*)W;
    float4* Ws4 = (float4*)Ws;
    #pragma unroll
    for (int i = 0; i < 4; ++i) Ws4[tid + 256 * i] = W4[tid + 256 * i];
    int base = bid * 16;                        // 3125*16 == N_NODES exactly
    ((float4*)xs)[tid] = ((const float4*)(x + (size_t)base * DIM))[tid];
    __syncthreads();                            // vmcnt(0): atomic result ready

    // ---- scatter: fire-and-forget, drains under the GEMM loop ----
    if (r < MAXDEG)
        elist[((size_t)edst << 7) + r] = make_int2(esrc, __float_as_int(ea));

    // ---- xm part: xm[n,d] = sum_k x[n,k]*W[k,d] + b_msg[d] + b_edge[d] ----
    int w = tid >> 6;                 // wave -> rows base+4w..+3
    int d = tid & 63;
    float bias = b_msg[d] + b_edge[d];
    float s0 = bias, s1 = bias, s2 = bias, s3 = bias;
    const float* xr = xs + (w * 4) * DIM;
    #pragma unroll
    for (int k = 0; k < DIM; ++k) {
        float wv = Ws[k * DIM + d];   // vector read, 2 lanes/bank = free
        s0 = fmaf(xr[k], wv, s0);     // xs reads are uniform broadcasts
        s1 = fmaf(xr[DIM + k], wv, s1);
        s2 = fmaf(xr[2 * DIM + k], wv, s2);
        s3 = fmaf(xr[3 * DIM + k], wv, s3);
    }
    _Float16* o = xmh + ((size_t)base + w * 4) * DIM + d;
    o[0] = (_Float16)s0;
    o[DIM] = (_Float16)s1;
    o[2 * DIM] = (_Float16)s2;
    o[3 * DIM] = (_Float16)s3;
}

// K2: wave per destination; 8 groups x 8 lanes; 8 edges per iteration.
// Each group keeps an independent online-softmax state over its strided 1/8
// of the bucket; merged at the end. Exact: max-aggregation commutes with the
// uniform positive rescale.  (UNCHANGED this round.)
__global__ __launch_bounds__(256) void k_aggregate(const half8* __restrict__ xm8,
                                                   const int2* __restrict__ elist,
                                                   const unsigned* __restrict__ cnt,
                                                   const float4* __restrict__ W_edge4,
                                                   const float4* __restrict__ att4,
                                                   const float4* __restrict__ x4,
                                                   float4* __restrict__ out4) {
    int node = blockIdx.x * 4 + (threadIdx.x >> 6);
    int lane = threadIdx.x & 63;
    int g = lane >> 3, t = lane & 7;
    unsigned deg = cnt[node];
    if (deg > MAXDEG) deg = MAXDEG;
    size_t obase = (size_t)node * 16 + 2 * t;
    if (deg == 0) {
        if (g == 0) { out4[obase] = x4[obase]; out4[obase + 1] = x4[obase + 1]; }
        return;
    }
    unsigned beg = (unsigned)node << 7;
    unsigned end = beg + deg;
    float4 wa = W_edge4[2 * t], wb = W_edge4[2 * t + 1];
    float4 aa = att4[2 * t],    ab = att4[2 * t + 1];
    float we[8] = {wa.x, wa.y, wa.z, wa.w, wb.x, wb.y, wb.z, wb.w};
    float at[8] = {aa.x, aa.y, aa.z, aa.w, ab.x, ab.y, ab.z, ab.w};

    unsigned idx = beg + (unsigned)g;
    bool act = idx < end;
    int2 e = elist[act ? idx : beg];
    half8 h = xm8[(size_t)e.x * 8 + t];

    float m = NEG_INF, denom = 0.f;
    float v[8];
    #pragma unroll
    for (int k = 0; k < 8; ++k) v[k] = 0.f;
    bool first = true;

    for (unsigned b = beg;; b += 8) {
        bool more = (b + 8) < end;         // wave-uniform
        int2 e2; half8 h2; bool a2 = false;
        if (more) {                        // prefetch next 8 edges
            unsigned i2 = b + 8 + (unsigned)g;
            a2 = i2 < end;
            e2 = elist[a2 ? i2 : beg];
            h2 = xm8[(size_t)e2.x * 8 + t];
        }
        float ea = __int_as_float(e.y);
        float msg[8];
        float p = 0.f;
        #pragma unroll
        for (int k = 0; k < 8; ++k) {
            float f = (float)h[k];
            msg[k] = fmaf(ea, we[k], f);
            float lr = fmaxf(msg[k], NEG_SLOPE * msg[k]);   // leaky (slope<1)
            p = fmaf(lr, at[k], p);
        }
        p += __shfl_xor(p, 1, 64);
        p += __shfl_xor(p, 2, 64);
        p += __shfl_xor(p, 4, 64);          // group-uniform logit
        if (first) {
            if (act) {
                m = p; denom = 1.f;
                #pragma unroll
                for (int k = 0; k < 8; ++k) v[k] = msg[k];
            }
            first = false;
        } else if (act) {
            float M = fmaxf(m, p);
            float so = __expf(m - M);
            float sn = __expf(p - M);
            denom = fmaf(denom, so, sn);
            #pragma unroll
            for (int k = 0; k < 8; ++k)
                v[k] = fmaxf(v[k] * so, msg[k] * sn);
            m = M;
        }
        if (!more) break;
        e = e2; h = h2; act = a2;
    }
    // merge the 8 per-group states
    bool has = denom > 0.f;
    float Ms = m;
    Ms = fmaxf(Ms, __shfl_xor(Ms, 8, 64));
    Ms = fmaxf(Ms, __shfl_xor(Ms, 16, 64));
    Ms = fmaxf(Ms, __shfl_xor(Ms, 32, 64));
    float s = has ? __expf(m - Ms) : 0.f;
    float dd = denom * s;
    dd += __shfl_xor(dd, 8, 64);
    dd += __shfl_xor(dd, 16, 64);
    dd += __shfl_xor(dd, 32, 64);
    float gv[8];
    #pragma unroll
    for (int k = 0; k < 8; ++k) {
        float gk = has ? v[k] * s : NEG_INF;
        gk = fmaxf(gk, __shfl_xor(gk, 8, 64));
        gk = fmaxf(gk, __shfl_xor(gk, 16, 64));
        gk = fmaxf(gk, __shfl_xor(gk, 32, 64));
        gv[k] = gk;
    }
    if (g == 0) {
        float inv = 1.0f / (dd + 1e-16f);
        float4 xa = x4[obase], xb = x4[obase + 1];
        float4 r0, r1;
        r0.x = fmaf(gv[0], inv, xa.x);
        r0.y = fmaf(gv[1], inv, xa.y);
        r0.z = fmaf(gv[2], inv, xa.z);
        r0.w = fmaf(gv[3], inv, xa.w);
        r1.x = fmaf(gv[4], inv, xb.x);
        r1.y = fmaf(gv[5], inv, xb.y);
        r1.z = fmaf(gv[6], inv, xb.z);
        r1.w = fmaf(gv[7], inv, xb.w);
        out4[obase] = r0;
        out4[obase + 1] = r1;
    }
}

extern "C" void kernel_launch(void* const* d_in, const int* in_sizes, int n_in,
                              void* d_out, int out_size, void* d_ws, size_t ws_size,
                              hipStream_t stream) {
    const float* x      = (const float*)d_in[0];
    const int*   eidx   = (const int*)d_in[1];     // [2, E] int32
    const float* eattr  = (const float*)d_in[2];
    const float* W_msg  = (const float*)d_in[3];
    const float* b_msg  = (const float*)d_in[4];
    const float* W_edge = (const float*)d_in[5];   // [1, D]
    const float* b_edge = (const float*)d_in[6];
    const float* att    = (const float*)d_in[7];
    float* out = (float*)d_out;

    // Workspace layout (~58 MB of 256 MiB):
    //   xmh:   N*64 fp16          6.4 MB
    //   elist: N*128 int2 buckets 51.2 MB (sparse-touched)
    //   cnt:   N u32              0.2 MB  -- zeroed
    _Float16* xmh   = (_Float16*)d_ws;
    int2*     elist = (int2*)(xmh + (size_t)N_NODES * DIM);
    unsigned* cnt   = (unsigned*)(elist + (size_t)N_NODES * MAXDEG);

    hipMemsetAsync(cnt, 0, (size_t)N_NODES * 4, stream);

    k_pre<<<NB, 256, 0, stream>>>(x, W_msg, b_msg, b_edge, xmh,
                                  eidx, eattr, cnt, elist);
    k_aggregate<<<N_NODES / 4, 256, 0, stream>>>(
        (const half8*)xmh, elist, cnt, (const float4*)W_edge,
        (const float4*)att, (const float4*)x, (float4*)out);
}

// Round 2
// 154.421 us; speedup vs baseline: 1.0186x; 1.0028x over previous
//
#include <hip/hip_runtime.h>

#define N_NODES 50000
#define N_EDGES 800000
#define DIM 64
#define NEG_SLOPE 0.2f
#define NEG_INF (-__builtin_inff())
#define NB      3125         // 3125 blocks: 16 GEMM rows + 256 edges each (exact)
#define MAXDEG  128          // bucket capacity; Poisson(16) => P(>=128) ~ e^-90

typedef _Float16 half8 __attribute__((ext_vector_type(8)));

// K1 (uniform fusion): EVERY block does 16 rows of xm = x@W + bias AND 256
// edges of histogram+scatter (1 edge/thread). UNCHANGED this round — at
// ~52 us with WRITE_SIZE ~= 800K lines it sits near the random-scatter
// floor for arrival-order -> dst-order movement of a random graph.
__global__ __launch_bounds__(256) void k_pre(const float* __restrict__ x,
                                             const float* __restrict__ W,
                                             const float* __restrict__ b_msg,
                                             const float* __restrict__ b_edge,
                                             _Float16* __restrict__ xmh,
                                             const int* __restrict__ eidx,
                                             const float* __restrict__ eattr,
                                             unsigned* __restrict__ cnt,
                                             int2* __restrict__ elist) {
    __shared__ float Ws[DIM * DIM];   // 16 KB, row-major (scalar reads: 0-conflict)
    __shared__ float xs[16 * DIM];    // 4 KB
    int tid = threadIdx.x;
    int bid = blockIdx.x;

    // ---- edge part: issue loads + atomic FIRST (latency hidden below) ----
    int e = bid * 256 + tid;                    // 3125*256 == N_EDGES exactly
    int    esrc = eidx[e];
    int    edst = eidx[N_EDGES + e];
    float  ea   = eattr[e];
    unsigned r  = atomicAdd(cnt + edst, 1u);    // rank == final slot

    // ---- stage W (16 KB) and 16 rows of x into LDS ----
    const float4* W4 = (const float4*)W;
    float4* Ws4 = (float4*)Ws;
    #pragma unroll
    for (int i = 0; i < 4; ++i) Ws4[tid + 256 * i] = W4[tid + 256 * i];
    int base = bid * 16;                        // 3125*16 == N_NODES exactly
    ((float4*)xs)[tid] = ((const float4*)(x + (size_t)base * DIM))[tid];
    __syncthreads();                            // vmcnt(0): atomic result ready

    // ---- scatter: fire-and-forget, drains under the GEMM loop ----
    if (r < MAXDEG)
        elist[((size_t)edst << 7) + r] = make_int2(esrc, __float_as_int(ea));

    // ---- xm part: xm[n,d] = sum_k x[n,k]*W[k,d] + b_msg[d] + b_edge[d] ----
    int w = tid >> 6;                 // wave -> rows base+4w..+3
    int d = tid & 63;
    float bias = b_msg[d] + b_edge[d];
    float s0 = bias, s1 = bias, s2 = bias, s3 = bias;
    const float* xr = xs + (w * 4) * DIM;
    #pragma unroll
    for (int k = 0; k < DIM; ++k) {
        float wv = Ws[k * DIM + d];   // vector read, 2 lanes/bank = free
        s0 = fmaf(xr[k], wv, s0);     // xs reads are uniform broadcasts
        s1 = fmaf(xr[DIM + k], wv, s1);
        s2 = fmaf(xr[2 * DIM + k], wv, s2);
        s3 = fmaf(xr[3 * DIM + k], wv, s3);
    }
    _Float16* o = xmh + ((size_t)base + w * 4) * DIM + d;
    o[0] = (_Float16)s0;
    o[DIM] = (_Float16)s1;
    o[2 * DIM] = (_Float16)s2;
    o[3 * DIM] = (_Float16)s3;
}

// K2 (RESTRUCTURED): one 8-lane GROUP per node (8 nodes/wave, 32/block).
// Replaces wave-per-node + 8-way strided groups + cross-group merge.
// Rationale (theory-first): at avg deg 16, the old per-node merge cost
// (~36 cross-lane ops x 64 lanes) EXCEEDED the per-node edge work
// (2 iters x 64 lanes x ~10 VALU). Group-per-node eliminates the merge
// entirely; the sequential bucket walk (deg ~16 iterations, 1-deep
// prefetch) also gives a much deeper gather pipeline than the old
// 2-iteration loop. Lane waste = wave runs max-deg of its 8 nodes
// (~23 for Poisson 16) with exec-masking — cheaper than the merge.
// Math identical: running max is exact; max-aggregation commutes with
// the uniform positive rescale; eps placement 1/(denom+1e-16) matches.
__global__ __launch_bounds__(256) void k_aggregate(const half8* __restrict__ xm8,
                                                   const int2* __restrict__ elist,
                                                   const unsigned* __restrict__ cnt,
                                                   const float4* __restrict__ W_edge4,
                                                   const float4* __restrict__ att4,
                                                   const float4* __restrict__ x4,
                                                   float4* __restrict__ out4) {
    int lane = threadIdx.x & 63;
    int wv   = threadIdx.x >> 6;
    int g = lane >> 3, t = lane & 7;
    int node = (blockIdx.x * 4 + wv) * 8 + g;
    if (node >= N_NODES) return;
    unsigned deg = cnt[node];
    if (deg > MAXDEG) deg = MAXDEG;
    size_t obase = (size_t)node * 16 + 2 * t;
    if (deg == 0) {
        out4[obase] = x4[obase];
        out4[obase + 1] = x4[obase + 1];
        return;
    }
    float4 wa = W_edge4[2 * t], wb = W_edge4[2 * t + 1];
    float4 aa = att4[2 * t],    ab = att4[2 * t + 1];
    float we[8] = {wa.x, wa.y, wa.z, wa.w, wb.x, wb.y, wb.z, wb.w};
    float at[8] = {aa.x, aa.y, aa.z, aa.w, ab.x, ab.y, ab.z, ab.w};

    unsigned beg = (unsigned)node << 7;
    // peeled pipeline: load edge i, prefetch i+1, compute i
    int2  e = elist[beg];                    // deg >= 1 guaranteed here
    half8 h = xm8[(size_t)e.x * 8 + t];      // group's 8 lanes cover the 128B row

    float m = NEG_INF, denom = 0.f;
    float v[8];
    #pragma unroll
    for (int k = 0; k < 8; ++k) v[k] = 0.f;

    unsigned i = 0;
    while (true) {
        bool more = (i + 1) < deg;           // group-uniform (divergent across groups)
        int2 e2; half8 h2;
        if (more) {                          // prefetch next edge of this bucket
            e2 = elist[beg + i + 1];
            h2 = xm8[(size_t)e2.x * 8 + t];
        }
        float ea = __int_as_float(e.y);
        float msg[8];
        float p = 0.f;
        #pragma unroll
        for (int k = 0; k < 8; ++k) {
            float f = (float)h[k];
            msg[k] = fmaf(ea, we[k], f);
            float lr = fmaxf(msg[k], NEG_SLOPE * msg[k]);   // leaky (slope<1)
            p = fmaf(lr, at[k], p);
        }
        p += __shfl_xor(p, 1, 64);
        p += __shfl_xor(p, 2, 64);
        p += __shfl_xor(p, 4, 64);           // group-uniform logit (xor<8 stays in group)
        if (i == 0) {
            m = p; denom = 1.f;
            #pragma unroll
            for (int k = 0; k < 8; ++k) v[k] = msg[k];
        } else {
            float M  = fmaxf(m, p);
            float so = __expf(m - M);
            float sn = __expf(p - M);
            denom = fmaf(denom, so, sn);
            #pragma unroll
            for (int k = 0; k < 8; ++k)
                v[k] = fmaxf(v[k] * so, msg[k] * sn);
            m = M;
        }
        if (!more) break;
        e = e2; h = h2; ++i;
    }
    // no cross-group merge needed: this group owns the whole bucket
    float inv = 1.0f / (denom + 1e-16f);
    float4 xa = x4[obase], xb = x4[obase + 1];
    float4 r0, r1;
    r0.x = fmaf(v[0], inv, xa.x);
    r0.y = fmaf(v[1], inv, xa.y);
    r0.z = fmaf(v[2], inv, xa.z);
    r0.w = fmaf(v[3], inv, xa.w);
    r1.x = fmaf(v[4], inv, xb.x);
    r1.y = fmaf(v[5], inv, xb.y);
    r1.z = fmaf(v[6], inv, xb.z);
    r1.w = fmaf(v[7], inv, xb.w);
    out4[obase] = r0;                        // wave writes 8 consecutive nodes: 2KB contiguous
    out4[obase + 1] = r1;
}

extern "C" void kernel_launch(void* const* d_in, const int* in_sizes, int n_in,
                              void* d_out, int out_size, void* d_ws, size_t ws_size,
                              hipStream_t stream) {
    const float* x      = (const float*)d_in[0];
    const int*   eidx   = (const int*)d_in[1];     // [2, E] int32
    const float* eattr  = (const float*)d_in[2];
    const float* W_msg  = (const float*)d_in[3];
    const float* b_msg  = (const float*)d_in[4];
    const float* W_edge = (const float*)d_in[5];   // [1, D]
    const float* b_edge = (const float*)d_in[6];
    const float* att    = (const float*)d_in[7];
    float* out = (float*)d_out;

    // Workspace layout (~58 MB of 256 MiB):
    //   xmh:   N*64 fp16          6.4 MB
    //   elist: N*128 int2 buckets 51.2 MB (sparse-touched)
    //   cnt:   N u32              0.2 MB  -- zeroed
    _Float16* xmh   = (_Float16*)d_ws;
    int2*     elist = (int2*)(xmh + (size_t)N_NODES * DIM);
    unsigned* cnt   = (unsigned*)(elist + (size_t)N_NODES * MAXDEG);

    hipMemsetAsync(cnt, 0, (size_t)N_NODES * 4, stream);

    k_pre<<<NB, 256, 0, stream>>>(x, W_msg, b_msg, b_edge, xmh,
                                  eidx, eattr, cnt, elist);
    // 8 nodes per wave, 32 per block
    k_aggregate<<<(N_NODES + 31) / 32, 256, 0, stream>>>(
        (const half8*)xmh, elist, cnt, (const float4*)W_edge,
        (const float4*)att, (const float4*)x, (float4*)out);
}